// Round 3
// baseline (32.695 us; speedup 1.0000x reference)
//
#include <hip/hip_runtime.h>
#include <math.h>

#define BB 16
#define PP 20
#define NP 17
#define DD 32
#define HH 128
#define WW 128
#define HWN (HH*WW)
#define CC (NP*DD)   // 544

// Block-wide sum for 256 threads (4 wave64s). Valid on thread 0 only.
__device__ __forceinline__ float block_sum_256(float v, float* wsum) {
    #pragma unroll
    for (int off = 32; off > 0; off >>= 1) v += __shfl_down(v, off);
    if ((threadIdx.x & 63) == 0) wsum[threadIdx.x >> 6] = v;
    __syncthreads();
    float t = 0.f;
    if (threadIdx.x == 0) t = wsum[0] + wsum[1] + wsum[2] + wsum[3];
    return t;
}

// One fused kernel. Phase A (all 320 blocks): gather 17x32 vecs for (b,p),
// mean + pull partial. The 20th block to finish within batch b (per-batch
// counter) runs phase B: push term for b + pull fold -> partial_b[b]. The
// 16th phase-B block sums partials in fixed order and writes the scalar.
__global__ __launch_bounds__(256) void ae_fused(
        const float* __restrict__ ebd, const float* __restrict__ kpts,
        float* __restrict__ means, float* __restrict__ pull_pp,
        float* __restrict__ partial_b, unsigned int* __restrict__ bcnt,
        unsigned int* __restrict__ fcnt, float* __restrict__ out) {
    const int bp  = blockIdx.x;        // b*PP + p
    const int b   = bp / PP;
    const int tid = threadIdx.x;

    __shared__ float vec_t[CC];        // transposed: [d*17 + k] == [j]
    __shared__ int   lin_s[NP];
    __shared__ float mean_s[DD];
    __shared__ float wsum[4];
    __shared__ int   flag;
    __shared__ float msh[PP * DD];

    if (tid < NP) {
        float2 kv = reinterpret_cast<const float2*>(kpts)[bp * NP + tid];
        int y = min(max((int)floorf(kv.x * (float)HH), 0), HH - 1);
        int x = min(max((int)floorf(kv.y * (float)WW), 0), WW - 1);
        lin_s[tid] = y * WW + x;
    }
    __syncthreads();

    // Gather: lane j -> (k = j%17, d = j/17); channel index k*32+d.
    // Wave addresses mix different lin_s[k] -> no common 64KB lattice.
    const float* base = ebd + (size_t)b * CC * HWN;
    #pragma unroll 3
    for (int j = tid; j < CC; j += 256) {
        int d = j / NP;
        int k = j - d * NP;
        vec_t[j] = base[(size_t)(k * DD + d) * HWN + lin_s[k]];
    }
    __syncthreads();

    if (tid < DD) {
        float s = 0.f;
        #pragma unroll
        for (int k = 0; k < NP; ++k) s += vec_t[tid * NP + k];
        float m = s * (1.0f / (float)NP);
        mean_s[tid] = m;
        means[bp * DD + tid] = m;
    }
    __syncthreads();

    float ps = 0.f;
    #pragma unroll 3
    for (int j = tid; j < CC; j += 256)
        ps += fabsf(vec_t[j] - mean_s[j / NP]);

    float tot = block_sum_256(ps, wsum);
    if (tid == 0) {
        __hip_atomic_store(&pull_pp[bp], tot * (1.0f / (float)CC),
                           __ATOMIC_RELEASE, __HIP_MEMORY_SCOPE_AGENT);
        unsigned int old = __hip_atomic_fetch_add(&bcnt[b], 1u, __ATOMIC_ACQ_REL,
                                                  __HIP_MEMORY_SCOPE_AGENT);
        flag = (old == PP - 1);
    }
    __syncthreads();
    if (!flag) return;

    // ---- Phase B: push for batch b (means of all 20 persons now visible;
    // acquire loads bypass L1 so no stale lines from poison/prior replay).
    for (int i = tid; i < PP * DD; i += 256)
        msh[i] = __hip_atomic_load(&means[b * PP * DD + i], __ATOMIC_ACQUIRE,
                                   __HIP_MEMORY_SCOPE_AGENT);
    __syncthreads();

    float acc = 0.f;
    if (tid < PP * (DD / 4)) {
        int p  = tid >> 3;
        int d4 = tid & 7;
        float4 mp = *reinterpret_cast<const float4*>(&msh[p * DD + d4 * 4]);
        #pragma unroll
        for (int q = 0; q < PP; ++q) {
            float4 mq = *reinterpret_cast<const float4*>(&msh[q * DD + d4 * 4]);
            acc += fabsf(mp.x - mq.x) + fabsf(mp.y - mq.y)
                 + fabsf(mp.z - mq.z) + fabsf(mp.w - mq.w);
        }
    }
    float v = acc * (1.0f / (float)(PP * PP * DD));
    if (tid < PP)
        v += __hip_atomic_load(&pull_pp[b * PP + tid], __ATOMIC_ACQUIRE,
                               __HIP_MEMORY_SCOPE_AGENT);

    float tot2 = block_sum_256(v, wsum);
    if (tid == 0) {
        __hip_atomic_store(&partial_b[b], tot2, __ATOMIC_RELEASE,
                           __HIP_MEMORY_SCOPE_AGENT);
        unsigned int o2 = __hip_atomic_fetch_add(fcnt, 1u, __ATOMIC_ACQ_REL,
                                                 __HIP_MEMORY_SCOPE_AGENT);
        if (o2 == BB - 1) {
            float s = 0.f;
            #pragma unroll
            for (int i = 0; i < BB; ++i)
                s += __hip_atomic_load(&partial_b[i], __ATOMIC_ACQUIRE,
                                       __HIP_MEMORY_SCOPE_AGENT);
            out[0] = s * (1.0f / (2.0f * (float)BB));
        }
    }
}

extern "C" void kernel_launch(void* const* d_in, const int* in_sizes, int n_in,
                              void* d_out, int out_size, void* d_ws, size_t ws_size,
                              hipStream_t stream) {
    const float* ebd  = (const float*)d_in[0];   // [16, 544, 128, 128] f32
    const float* kpts = (const float*)d_in[1];   // [16, 20, 17, 2] f32
    float* out = (float*)d_out;                  // scalar f32

    float* ws             = (float*)d_ws;
    float* means          = ws;                       // 10240 floats
    float* pull_pp        = means + BB * PP * DD;     // 320 floats
    float* partial_b      = pull_pp + BB * PP;        // 16 floats
    unsigned int* bcnt    = (unsigned int*)(partial_b + BB);  // 16 uints
    unsigned int* fcnt    = bcnt + BB;                        // 1 uint

    // Counters must be zero each call (ws is poisoned once, not re-poisoned):
    // a 68-byte memset node is the cheapest way to get a pre-kernel zero.
    hipMemsetAsync(bcnt, 0, (BB + 1) * sizeof(unsigned int), stream);
    ae_fused<<<BB * PP, 256, 0, stream>>>(ebd, kpts, means, pull_pp,
                                          partial_b, bcnt, fcnt, out);
}

// Round 4
// 16.331 us; speedup vs baseline: 2.0020x; 2.0020x over previous
//
#include <hip/hip_runtime.h>
#include <math.h>

#define BB 16
#define PP 20
#define NP 17
#define DD 32
#define HH 128
#define WW 128
#define HWN (HH*WW)
#define CC (NP*DD)   // 544

// K1 — one block per (b,p), 576 threads (9 waves): thread tid<544 gathers
// channel tid (= k*32+d) at that part's keypoint, one global round. Mean via
// LDS, pull from the register copy. Block 0 zeroes k2's arrival counter
// (ordered by the dispatch boundary — NOT a graph memset node; R3 showed
// memset nodes cost ~16us).
__global__ __launch_bounds__(576) void k1_gather_pull(
        const float* __restrict__ ebd, const float* __restrict__ kpts,
        float* __restrict__ means, float* __restrict__ pull_pp,
        unsigned int* __restrict__ fcnt) {
    const int bp  = blockIdx.x;        // b*PP + p
    const int b   = bp / PP;
    const int tid = threadIdx.x;

    if (bp == 0 && tid == 0) *fcnt = 0u;

    __shared__ float vec[CC];          // [k*32 + d]
    __shared__ float mean_s[DD];
    __shared__ float wsum[9];

    float v = 0.f;
    if (tid < CC) {
        int k = tid >> 5;              // part
        float2 kv = reinterpret_cast<const float2*>(kpts)[bp * NP + k];
        int y = min(max((int)floorf(kv.x * (float)HH), 0), HH - 1);
        int x = min(max((int)floorf(kv.y * (float)WW), 0), WW - 1);
        v = ebd[(size_t)b * CC * HWN + (size_t)tid * HWN + (y * WW + x)];
        vec[tid] = v;
    }
    __syncthreads();

    if (tid < DD) {
        float s = 0.f;
        #pragma unroll
        for (int k = 0; k < NP; ++k) s += vec[k * DD + tid];
        float m = s * (1.0f / (float)NP);
        mean_s[tid] = m;
        means[bp * DD + tid] = m;
    }
    __syncthreads();

    float ps = (tid < CC) ? fabsf(v - mean_s[tid & (DD - 1)]) : 0.f;
    #pragma unroll
    for (int off = 32; off > 0; off >>= 1) ps += __shfl_down(ps, off);
    if ((tid & 63) == 0) wsum[tid >> 6] = ps;
    __syncthreads();
    if (tid == 0) {
        float t = 0.f;
        #pragma unroll
        for (int w = 0; w < 9; ++w) t += wsum[w];
        pull_pp[bp] = t * (1.0f / (float)CC);
    }
}

// K2 — one block per batch b: push term (register-blocked float4, full PxP
// including diagonal) + this batch's pull partials -> partial_b[b]. Last
// block to arrive sums the 16 partials in fixed order, writes the scalar.
__global__ __launch_bounds__(256) void k2_push_final(
        const float* __restrict__ means, const float* __restrict__ pull_pp,
        float* __restrict__ partial_b, unsigned int* __restrict__ fcnt,
        float* __restrict__ out) {
    const int b   = blockIdx.x;
    const int tid = threadIdx.x;

    __shared__ float m[PP * DD];
    __shared__ float wsum[4];

    for (int i = tid; i < PP * DD; i += 256)
        m[i] = means[b * PP * DD + i];
    __syncthreads();

    float acc = 0.f;
    if (tid < PP * (DD / 4)) {
        int p  = tid >> 3;
        int d4 = tid & 7;
        float4 mp = *reinterpret_cast<const float4*>(&m[p * DD + d4 * 4]);
        #pragma unroll
        for (int q = 0; q < PP; ++q) {
            float4 mq = *reinterpret_cast<const float4*>(&m[q * DD + d4 * 4]);
            acc += fabsf(mp.x - mq.x) + fabsf(mp.y - mq.y)
                 + fabsf(mp.z - mq.z) + fabsf(mp.w - mq.w);
        }
    }
    float v = acc * (1.0f / (float)(PP * PP * DD));
    if (tid < PP) v += pull_pp[b * PP + tid];

    #pragma unroll
    for (int off = 32; off > 0; off >>= 1) v += __shfl_down(v, off);
    if ((tid & 63) == 0) wsum[tid >> 6] = v;
    __syncthreads();

    if (tid == 0) {
        float tot = wsum[0] + wsum[1] + wsum[2] + wsum[3];
        __hip_atomic_store(&partial_b[b], tot, __ATOMIC_RELEASE,
                           __HIP_MEMORY_SCOPE_AGENT);
        unsigned int old = __hip_atomic_fetch_add(fcnt, 1u, __ATOMIC_ACQ_REL,
                                                  __HIP_MEMORY_SCOPE_AGENT);
        if (old == BB - 1) {
            float s = 0.f;
            #pragma unroll
            for (int i = 0; i < BB; ++i)
                s += __hip_atomic_load(&partial_b[i], __ATOMIC_ACQUIRE,
                                       __HIP_MEMORY_SCOPE_AGENT);
            out[0] = s * (1.0f / (2.0f * (float)BB));
        }
    }
}

extern "C" void kernel_launch(void* const* d_in, const int* in_sizes, int n_in,
                              void* d_out, int out_size, void* d_ws, size_t ws_size,
                              hipStream_t stream) {
    const float* ebd  = (const float*)d_in[0];   // [16, 544, 128, 128] f32
    const float* kpts = (const float*)d_in[1];   // [16, 20, 17, 2] f32
    float* out = (float*)d_out;                  // scalar f32

    float* ws          = (float*)d_ws;
    float* means       = ws;                      // 10240 floats
    float* pull_pp     = means + BB * PP * DD;    // 320 floats
    float* partial_b   = pull_pp + BB * PP;       // 16 floats
    unsigned int* fcnt = (unsigned int*)(partial_b + BB);

    k1_gather_pull<<<BB * PP, 576, 0, stream>>>(ebd, kpts, means, pull_pp, fcnt);
    k2_push_final<<<BB, 256, 0, stream>>>(means, pull_pp, partial_b, fcnt, out);
}